// Round 12
// baseline (559.760 us; speedup 1.0000x reference)
//
#include <hip/hip_runtime.h>

#define DEVINL __device__ __forceinline__

// Exact (no-FMA-contraction) squared distance in the same rounding order as
// numpy/jax fp32: ((dx*dx + dy*dy) + dz*dz). Discrete decisions (FPS argmax,
// ball-query radius compare) depend on bit-exactness.
DEVINL float sq3(float ax, float ay, float az, float bx, float by, float bz) {
  float dx = __fsub_rn(ax, bx), dy = __fsub_rn(ay, by), dz = __fsub_rn(az, bz);
  return __fadd_rn(__fadd_rn(__fmul_rn(dx, dx), __fmul_rn(dy, dy)), __fmul_rn(dz, dz));
}

DEVINL float rdlane(float v, int l) {  // l compile-time const in unrolled loops
  return __int_as_float(__builtin_amdgcn_readlane(__float_as_int(v), l));
}

// DPP max-trees (VALU pipe). old=own so invalid-lane results are identity-safe
// for max. row_shr:1/2/4/8 + row_bcast:15 (+ row_bcast:31) -> 32/64-lane max;
// 64-lane result valid at lane 63 (proven rounds 4-11, absmax 0.0).
template <int CTRL>
DEVINL float dpp_maxf(float v) {
  int o = __builtin_amdgcn_update_dpp(__float_as_int(v), __float_as_int(v),
                                      CTRL, 0xf, 0xf, false);
  return fmaxf(v, __int_as_float(o));
}
DEVINL float red32_maxf(float v) {
  v = dpp_maxf<0x111>(v); v = dpp_maxf<0x112>(v); v = dpp_maxf<0x114>(v);
  v = dpp_maxf<0x118>(v); v = dpp_maxf<0x142>(v);
  return v;
}
DEVINL float red64_maxf(float v) {
  v = red32_maxf(v); v = dpp_maxf<0x143>(v);
  return v;
}
template <int CTRL>
DEVINL unsigned long long dpp_maxk(unsigned long long k) {
  const unsigned lo = (unsigned)k, hi = (unsigned)(k >> 32);
  const unsigned olo = (unsigned)__builtin_amdgcn_update_dpp(
      (int)lo, (int)lo, CTRL, 0xf, 0xf, false);
  const unsigned ohi = (unsigned)__builtin_amdgcn_update_dpp(
      (int)hi, (int)hi, CTRL, 0xf, 0xf, false);
  const unsigned long long ok = ((unsigned long long)ohi << 32) | olo;
  return (ok > k) ? ok : k;
}
DEVINL unsigned long long red64_maxk(unsigned long long k) {
  k = dpp_maxk<0x111>(k); k = dpp_maxk<0x112>(k); k = dpp_maxk<0x114>(k);
  k = dpp_maxk<0x118>(k); k = dpp_maxk<0x142>(k); k = dpp_maxk<0x143>(k);
  return k;
}

// ---------------------------------------------------------------------------
// K1: farthest point sampling. Round-6 wave structure (4 waves x 8 pts,
// empirical optimum over 1/4/8-wave variants) with two round-12 chain cuts:
//  (a) out[it] buffered in LDS, one global write after the loop -> the
//      __syncthreads-forced `s_waitcnt vmcnt(0)` no longer waits on a global
//      store ack every step (zero global ops in-loop);
//  (b) the winning LANE publishes the winner's coords straight from its
//      registers (bx/by/bz carried through the j-loop select chain,
//      compile-time j only) -> pre-barrier LDS coord read removed. Winner
//      identified by own-key == readlane(tree,63) (key embeds unique index ->
//      exactly one match). Packed-u64 key semantics unchanged (bit-exact).
// ---------------------------------------------------------------------------
__global__ __launch_bounds__(256) void k_fps(const float* __restrict__ xyz,
                                             int* __restrict__ fidx) {
  const int b = blockIdx.x, t = threadIdx.x;
  __shared__ float xs[2048], ys[2048], zs[2048];
  __shared__ unsigned long long skey[2][4];
  __shared__ float4 scoord[2][4];
  __shared__ int out_lds[512];
  const float* P = xyz + (size_t)b * 6144;
  for (int i = t; i < 2048; i += 256) {
    xs[i] = P[3 * i]; ys[i] = P[3 * i + 1]; zs[i] = P[3 * i + 2];
  }
  __syncthreads();
  float px[8], py[8], pz[8], dist[8];
#pragma unroll
  for (int j = 0; j < 8; ++j) {
    const int idx = j * 256 + t;
    px[j] = xs[idx]; py[j] = ys[idx]; pz[j] = zs[idx];
    dist[j] = 1e10f;
  }
  int far = 0;
  float cx = xs[0], cy = ys[0], cz = zs[0];
  for (int it = 0; it < 512; ++it) {
    if (t == 0) out_lds[it] = far;  // emit BEFORE update (scan semantics)
    float bv = -1.0f;
    int bi = 0;
    float bx = 0.f, by = 0.f, bz = 0.f;
#pragma unroll
    for (int j = 0; j < 8; ++j) {
      const float d = sq3(px[j], py[j], pz[j], cx, cy, cz);
      const float nd = fminf(dist[j], d);
      dist[j] = nd;
      if (nd > bv) {  // strict >: smallest idx kept (ascending j)
        bv = nd; bi = j * 256 + t;
        bx = px[j]; by = py[j]; bz = pz[j];
      }
    }
    // packed key: larger value wins; tie -> larger (2047-idx) -> smaller idx
    const unsigned long long key0 =
        ((unsigned long long)__float_as_uint(bv) << 32) | (unsigned)(2047 - bi);
    unsigned long long key = red64_maxk(key0);  // wave winner at lane 63
    const unsigned wlo = (unsigned)__builtin_amdgcn_readlane((int)(unsigned)key, 63);
    const unsigned whi = (unsigned)__builtin_amdgcn_readlane((int)(unsigned)(key >> 32), 63);
    const unsigned long long wkey = ((unsigned long long)whi << 32) | wlo;
    const int par = it & 1;
    if (key0 == wkey) {  // exactly one lane per wave (key embeds unique idx)
      skey[par][t >> 6] = wkey;
      scoord[par][t >> 6] = make_float4(bx, by, bz, 0.0f);
    }
    __syncthreads();
    unsigned long long k0 = skey[par][0], k1 = skey[par][1];
    unsigned long long k2 = skey[par][2], k3 = skey[par][3];
    float4 c0 = scoord[par][0], c1 = scoord[par][1];
    float4 c2 = scoord[par][2], c3 = scoord[par][3];
    if (k1 > k0) { k0 = k1; c0 = c1; }
    if (k3 > k2) { k2 = k3; c2 = c3; }
    if (k2 > k0) { k0 = k2; c0 = c2; }
    far = 2047 - (int)((unsigned)k0 & 2047u);
    cx = c0.x; cy = c0.y; cz = c0.z;
  }
  __syncthreads();
  int* out = fidx + b * 512;
  for (int i = t; i < 512; i += 256) out[i] = out_lds[i];
}

// ---------------------------------------------------------------------------
// K2: ball query. One wave per centroid. Writes the first-32 ascending
// in-radius indices to gidx[g*32 + pos] and the DISTINCT count to gn[g]
// (no padding: max over duplicates == max over distinct). Every group has
// >= 1 hit (its own centroid, d2 = 0 <= r2).
// ---------------------------------------------------------------------------
__global__ __launch_bounds__(256) void k_ballq(const float* __restrict__ xyz,
                                               const int* __restrict__ fidx,
                                               float* __restrict__ new_xyz,
                                               int* __restrict__ gidx,
                                               int* __restrict__ gn) {
  const int gw = (blockIdx.x * 256 + threadIdx.x) >> 6;  // centroid id
  const int lane = threadIdx.x & 63;
  const int b = gw >> 9;
  const float* P = xyz + (size_t)b * 6144;
  const int cidx = fidx[gw];
  const float cx = P[3 * cidx], cy = P[3 * cidx + 1], cz = P[3 * cidx + 2];
  if (lane < 3) new_xyz[(size_t)gw * 3 + lane] = P[3 * cidx + lane];
  int* g = gidx + (size_t)gw * 32;
  int base = 0;
  for (int c0 = 0; c0 < 2048; c0 += 64) {
    const int idx = c0 + lane;
    const float d = sq3(cx, cy, cz, P[3 * idx], P[3 * idx + 1], P[3 * idx + 2]);
    const bool in = !(d > 0.04f);  // matches: exclude where sqr > r*r
    const unsigned long long m = __ballot(in);
    if (in) {
      const int pos = base + (int)__popcll(m & ((1ull << lane) - 1ull));
      if (pos < 32) g[pos] = idx;
    }
    base += (int)__popcll(m);
    if (base >= 32) break;  // wave-uniform
  }
  if (lane == 0) gn[gw] = (base < 32) ? base : 32;
}

// ---------------------------------------------------------------------------
// K3: SA1, one WAVE per group, distinct items looped (E[n] ~ 2-3 of max 32).
// Register-only reduction: lane d computes h0[d]; cross-lane broadcast via
// v_readlane (compile-time lane index); lane owns sv[lane] and outputs
// {lane, lane+64}, max-accumulated in 2 VGPRs. Per-wave weight preload = 192
// VGPRs (launch_bounds(256,2) -> 256 cap). No atomics (round-10 lesson:
// device-scope atomicMax = ~30B fabric RMW each -> 113MB, 364us).
// ---------------------------------------------------------------------------
__global__ __launch_bounds__(256, 2) void k_sa1g(
    const float* __restrict__ xyz, const float* __restrict__ new_xyz,
    const int* __restrict__ gidx, const int* __restrict__ gn,
    const float* __restrict__ w0, const float* __restrict__ b0,
    const float* __restrict__ w1, const float* __restrict__ b1,
    const float* __restrict__ w2, const float* __restrict__ b2,
    float* __restrict__ l1p) {
  const int wv = threadIdx.x >> 6, lane = threadIdx.x & 63;
  const int g = blockIdx.x * 4 + wv;  // group id
  const int b = g >> 9;
  float w1r[64], w2ra[64], w2rb[64];
#pragma unroll
  for (int c = 0; c < 64; ++c) w1r[c] = w1[(lane << 6) + c];
#pragma unroll
  for (int c = 0; c < 64; ++c) w2ra[c] = w2[(lane << 6) + c];
#pragma unroll
  for (int c = 0; c < 64; ++c) w2rb[c] = w2[((lane + 64) << 6) + c];
  const float w0x = w0[3 * lane], w0y = w0[3 * lane + 1], w0z = w0[3 * lane + 2];
  const float b0l = b0[lane], b1l = b1[lane];
  const float b2a = b2[lane], b2b = b2[lane + 64];
  const float* P = xyz + (size_t)b * 6144;
  const float nx = new_xyz[(size_t)g * 3], ny = new_xyz[(size_t)g * 3 + 1],
              nz = new_xyz[(size_t)g * 3 + 2];
  const int n = gn[g];  // wave-uniform
  const int* items = gidx + (size_t)g * 32;
  float acca = 0.0f, accb = 0.0f;  // relu outputs >= 0 -> 0 is max-identity
  for (int i = 0; i < n; ++i) {
    const int src = items[i];  // wave-uniform
    const float x = P[3 * src] - nx, y = P[3 * src + 1] - ny,
                z = P[3 * src + 2] - nz;
    const float h = fmaxf(0.0f, fmaf(w0x, x, fmaf(w0y, y, fmaf(w0z, z, b0l))));
    float s0 = 0.f, s1 = 0.f, s2 = 0.f, s3 = 0.f;
#pragma unroll
    for (int c = 0; c < 64; c += 4) {
      s0 = fmaf(w1r[c], rdlane(h, c), s0);
      s1 = fmaf(w1r[c + 1], rdlane(h, c + 1), s1);
      s2 = fmaf(w1r[c + 2], rdlane(h, c + 2), s2);
      s3 = fmaf(w1r[c + 3], rdlane(h, c + 3), s3);
    }
    const float sv = fmaxf(0.0f, b1l + ((s0 + s1) + (s2 + s3)));
    float a0 = 0.f, a1 = 0.f, a2 = 0.f, a3 = 0.f;
    float u0 = 0.f, u1 = 0.f, u2 = 0.f, u3 = 0.f;
#pragma unroll
    for (int c = 0; c < 64; c += 4) {
      const float v0 = rdlane(sv, c), v1 = rdlane(sv, c + 1);
      const float v2 = rdlane(sv, c + 2), v3 = rdlane(sv, c + 3);
      a0 = fmaf(w2ra[c], v0, a0);
      a1 = fmaf(w2ra[c + 1], v1, a1);
      a2 = fmaf(w2ra[c + 2], v2, a2);
      a3 = fmaf(w2ra[c + 3], v3, a3);
      u0 = fmaf(w2rb[c], v0, u0);
      u1 = fmaf(w2rb[c + 1], v1, u1);
      u2 = fmaf(w2rb[c + 2], v2, u2);
      u3 = fmaf(w2rb[c + 3], v3, u3);
    }
    acca = fmaxf(acca, fmaxf(0.0f, b2a + ((a0 + a1) + (a2 + a3))));
    accb = fmaxf(accb, fmaxf(0.0f, b2b + ((u0 + u1) + (u2 + u3))));
  }
  float* outg = l1p + (size_t)g * 128;
  outg[lane] = acca;
  outg[lane + 64] = accb;
}

// ---------------------------------------------------------------------------
// SA2 layer kernels: lane = point (m), A row in registers (float4 packed
// [d/4][m][4] intermediates), weights via wave-uniform scalar path.
// 16-dim chunks for 2-4 blocks/CU latency hiding (round-6 win).
// ---------------------------------------------------------------------------
__global__ __launch_bounds__(256, 2) void k_sa2_l0(
    const float* __restrict__ new_xyz, const float* __restrict__ l1p,
    const float* __restrict__ w0, const float* __restrict__ b0,
    float4* __restrict__ h0t4) {
  const int pb = blockIdx.x >> 3, ds = blockIdx.x & 7;  // 8 chunks x 16 dims
  const int t = threadIdx.x;
  const int d0 = ds * 16;
  const int m = pb * 256 + t;
  const float ax = new_xyz[(size_t)m * 3], ay = new_xyz[(size_t)m * 3 + 1],
              az = new_xyz[(size_t)m * 3 + 2];
  float4 av[32];
  const float4* lp = (const float4*)(l1p + (size_t)m * 128);
#pragma unroll
  for (int i = 0; i < 32; ++i) av[i] = lp[i];
  for (int dq = 0; dq < 4; ++dq) {
    float o[4];
#pragma unroll
    for (int k = 0; k < 4; ++k) {
      const int dd = 4 * dq + k;
      const float* wr = w0 + (size_t)(d0 + dd) * 131;
      float s = fmaf(wr[0], ax, fmaf(wr[1], ay, fmaf(wr[2], az, b0[d0 + dd])));
      float s0 = 0.f, s1 = 0.f, s2 = 0.f, s3 = 0.f;
#pragma unroll
      for (int i = 0; i < 32; ++i) {
        s0 = fmaf(wr[3 + 4 * i], av[i].x, s0);
        s1 = fmaf(wr[4 + 4 * i], av[i].y, s1);
        s2 = fmaf(wr[5 + 4 * i], av[i].z, s2);
        s3 = fmaf(wr[6 + 4 * i], av[i].w, s3);
      }
      o[k] = fmaxf(0.0f, s + ((s0 + s1) + (s2 + s3)));
    }
    h0t4[(size_t)(ds * 4 + dq) * 16384 + m] =
        make_float4(o[0], o[1], o[2], o[3]);
  }
}

__global__ __launch_bounds__(256, 2) void k_sa2_l1(
    const float4* __restrict__ h0t4, const float* __restrict__ w1,
    const float* __restrict__ b1, float4* __restrict__ h1t4) {
  const int pb = blockIdx.x >> 3, ds = blockIdx.x & 7;  // 8 chunks x 16 dims
  const int t = threadIdx.x;
  const int d0 = ds * 16;
  const int m = pb * 256 + t;
  float4 a4[32];
#pragma unroll
  for (int i = 0; i < 32; ++i) a4[i] = h0t4[(size_t)i * 16384 + m];
  for (int dq = 0; dq < 4; ++dq) {
    float o[4];
#pragma unroll
    for (int k = 0; k < 4; ++k) {
      const int dd = 4 * dq + k;
      const float* wr = w1 + (size_t)(d0 + dd) * 128;
      float s0 = 0.f, s1 = 0.f, s2 = 0.f, s3 = 0.f;
#pragma unroll
      for (int i = 0; i < 32; ++i) {
        s0 = fmaf(wr[4 * i], a4[i].x, s0);
        s1 = fmaf(wr[4 * i + 1], a4[i].y, s1);
        s2 = fmaf(wr[4 * i + 2], a4[i].z, s2);
        s3 = fmaf(wr[4 * i + 3], a4[i].w, s3);
      }
      o[k] = fmaxf(0.0f, b1[d0 + dd] + ((s0 + s1) + (s2 + s3)));
    }
    h1t4[(size_t)(ds * 4 + dq) * 16384 + m] =
        make_float4(o[0], o[1], o[2], o[3]);
  }
}

__global__ __launch_bounds__(256, 2) void k_sa2_l2max(
    const float4* __restrict__ h1t4, const float* __restrict__ w2,
    const float* __restrict__ b2, float* __restrict__ pmax) {
  const int pb = blockIdx.x >> 4, ds = blockIdx.x & 15;  // 16 chunks x 16 dims
  const int t = threadIdx.x;
  const int d0 = ds * 16;
  const int m = pb * 256 + t;
  const int b = m >> 9;
  const int wc = ((pb << 2) + (t >> 6)) & 7;  // wave-chunk within batch (0..7)
  float4 a4[32];
#pragma unroll
  for (int i = 0; i < 32; ++i) a4[i] = h1t4[(size_t)i * 16384 + m];
  for (int dq = 0; dq < 4; ++dq) {
#pragma unroll
    for (int k = 0; k < 4; ++k) {
      const int dd = 4 * dq + k;
      const float* wr = w2 + (size_t)(d0 + dd) * 128;
      float s0 = 0.f, s1 = 0.f, s2 = 0.f, s3 = 0.f;
#pragma unroll
      for (int i = 0; i < 32; ++i) {
        s0 = fmaf(wr[4 * i], a4[i].x, s0);
        s1 = fmaf(wr[4 * i + 1], a4[i].y, s1);
        s2 = fmaf(wr[4 * i + 2], a4[i].z, s2);
        s3 = fmaf(wr[4 * i + 3], a4[i].w, s3);
      }
      float v = fmaxf(0.0f, b2[d0 + dd] + ((s0 + s1) + (s2 + s3)));
      v = red64_maxf(v);  // wave max, valid at lane 63
      if ((t & 63) == 63) pmax[((size_t)(b << 3) + wc) * 256 + d0 + dd] = v;
    }
  }
}

// ---------------------------------------------------------------------------
// K7: head. One block (1 wave) per batch. obj = max over 8 wave-partials,
// pose MLP + fusion MLP + two scalar heads.
// ---------------------------------------------------------------------------
__global__ __launch_bounds__(64) void k_head(
    const float* __restrict__ pmax, const float* __restrict__ grasp,
    const float* __restrict__ initp, const float* __restrict__ finalp,
    const int* __restrict__ surf, const float* __restrict__ embi,
    const float* __restrict__ embf, const float* __restrict__ pw0,
    const float* __restrict__ pb0, const float* __restrict__ pw1,
    const float* __restrict__ pb1, const float* __restrict__ pw2,
    const float* __restrict__ pb2, const float* __restrict__ fw0,
    const float* __restrict__ fb0, const float* __restrict__ fw1,
    const float* __restrict__ fb1, const float* __restrict__ osw,
    const float* __restrict__ osb, const float* __restrict__ ocw,
    const float* __restrict__ ocb, float* __restrict__ out) {
  __shared__ float obj[256], xb[37], A0[64], A1[128], A2[128], F0[128], HID[64];
  const int b = blockIdx.x, l = threadIdx.x;
  const float* pm = pmax + (size_t)b * 2048;
  for (int e = l; e < 256; e += 64) {
    float v = pm[e];
#pragma unroll
    for (int w = 1; w < 8; ++w) v = fmaxf(v, pm[w * 256 + e]);
    obj[e] = v;
  }
  if (l < 7) xb[l] = grasp[b * 7 + l];
  else if (l < 14) xb[l] = initp[b * 7 + l - 7];
  else if (l < 21) xb[l] = finalp[b * 7 + l - 14];
  else if (l < 29) xb[l] = embi[surf[b * 2] * 8 + l - 21];
  else if (l < 37) xb[l] = embf[surf[b * 2 + 1] * 8 + l - 29];
  __syncthreads();
  {
    float s = pb0[l];
    const float* wr = pw0 + l * 37;
#pragma unroll
    for (int c = 0; c < 37; ++c) s = fmaf(xb[c], wr[c], s);
    A0[l] = fmaxf(0.f, s);
  }
  __syncthreads();
#pragma unroll
  for (int dd = 0; dd < 2; ++dd) {
    const int d = l + dd * 64;
    float s = pb1[d];
    const float* wr = pw1 + d * 64;
#pragma unroll
    for (int c = 0; c < 64; ++c) s = fmaf(A0[c], wr[c], s);
    A1[d] = fmaxf(0.f, s);
  }
  __syncthreads();
#pragma unroll
  for (int dd = 0; dd < 2; ++dd) {
    const int d = l + dd * 64;
    float s = pb2[d];
    const float* wr = pw2 + d * 128;
#pragma unroll 16
    for (int c = 0; c < 128; ++c) s = fmaf(A1[c], wr[c], s);
    A2[d] = fmaxf(0.f, s);
  }
  __syncthreads();
#pragma unroll
  for (int dd = 0; dd < 2; ++dd) {
    const int d = l + dd * 64;
    float s = fb0[d];
    const float* wr = fw0 + d * 384;
#pragma unroll 16
    for (int c = 0; c < 256; ++c) s = fmaf(obj[c], wr[c], s);
#pragma unroll 16
    for (int c = 0; c < 128; ++c) s = fmaf(A2[c], wr[256 + c], s);
    F0[d] = fmaxf(0.f, s);
  }
  __syncthreads();
  {
    float s = fb1[l];
    const float* wr = fw1 + l * 128;
#pragma unroll 16
    for (int c = 0; c < 128; ++c) s = fmaf(F0[c], wr[c], s);
    HID[l] = fmaxf(0.f, s);
  }
  __syncthreads();
  float v1 = HID[l] * osw[l];
  float v2 = HID[l] * ocw[l];
#pragma unroll
  for (int off = 1; off < 64; off <<= 1) {
    v1 += __shfl_xor(v1, off);
    v2 += __shfl_xor(v2, off);
  }
  if (l == 0) {
    out[b] = v1 + osb[0];
    out[32 + b] = v2 + ocb[0];
  }
}

extern "C" void kernel_launch(void* const* d_in, const int* in_sizes, int n_in,
                              void* d_out, int out_size, void* d_ws, size_t ws_size,
                              hipStream_t stream) {
  const float* points  = (const float*)d_in[0];
  const float* grasp   = (const float*)d_in[1];
  const float* initp   = (const float*)d_in[2];
  const float* finalp  = (const float*)d_in[3];
  const int*   surf    = (const int*)d_in[4];
  const float* sa1_w0  = (const float*)d_in[5];
  const float* sa1_b0  = (const float*)d_in[6];
  const float* sa1_w1  = (const float*)d_in[7];
  const float* sa1_b1  = (const float*)d_in[8];
  const float* sa1_w2  = (const float*)d_in[9];
  const float* sa1_b2  = (const float*)d_in[10];
  const float* sa2_w0  = (const float*)d_in[11];
  const float* sa2_b0  = (const float*)d_in[12];
  const float* sa2_w1  = (const float*)d_in[13];
  const float* sa2_b1  = (const float*)d_in[14];
  const float* sa2_w2  = (const float*)d_in[15];
  const float* sa2_b2  = (const float*)d_in[16];
  const float* embi    = (const float*)d_in[17];
  const float* embf    = (const float*)d_in[18];
  const float* pe_w0   = (const float*)d_in[19];
  const float* pe_b0   = (const float*)d_in[20];
  const float* pe_w1   = (const float*)d_in[21];
  const float* pe_b1   = (const float*)d_in[22];
  const float* pe_w2   = (const float*)d_in[23];
  const float* pe_b2   = (const float*)d_in[24];
  const float* fu_w0   = (const float*)d_in[25];
  const float* fu_b0   = (const float*)d_in[26];
  const float* fu_w1   = (const float*)d_in[27];
  const float* fu_b1   = (const float*)d_in[28];
  const float* os_w    = (const float*)d_in[29];
  const float* os_b    = (const float*)d_in[30];
  const float* oc_w    = (const float*)d_in[31];
  const float* oc_b    = (const float*)d_in[32];

  char* ws = (char*)d_ws;
  // layout (bytes):
  int*    fidx    = (int*)(ws + 0);               //  65536
  float*  new_xyz = (float*)(ws + 65536);         // 196608
  int*    gidx    = (int*)(ws + 262144);          // 2097152 (16384*32*4)
  float*  l1p     = (float*)(ws + 2359296);       // 8388608 (reused as h1t)
  float4* h0t4    = (float4*)(ws + 10747904);     // 8388608
  float*  pmax    = (float*)(ws + 19136512);      // 262144
  int*    gn      = (int*)(ws + 19398656);        // 65536 -> end 19464192
  float4* h1t4    = (float4*)l1p;  // l1_points dead after k_sa2_l0

  float* out = (float*)d_out;

  k_fps<<<32, 256, 0, stream>>>(points, fidx);
  k_ballq<<<4096, 256, 0, stream>>>(points, fidx, new_xyz, gidx, gn);
  k_sa1g<<<4096, 256, 0, stream>>>(points, new_xyz, gidx, gn, sa1_w0, sa1_b0,
                                   sa1_w1, sa1_b1, sa1_w2, sa1_b2, l1p);
  k_sa2_l0<<<512, 256, 0, stream>>>(new_xyz, l1p, sa2_w0, sa2_b0, h0t4);
  k_sa2_l1<<<512, 256, 0, stream>>>(h0t4, sa2_w1, sa2_b1, h1t4);
  k_sa2_l2max<<<1024, 256, 0, stream>>>(h1t4, sa2_w2, sa2_b2, pmax);
  k_head<<<32, 64, 0, stream>>>(pmax, grasp, initp, finalp, surf, embi, embf,
                                pe_w0, pe_b0, pe_w1, pe_b1, pe_w2, pe_b2, fu_w0,
                                fu_b0, fu_w1, fu_b1, os_w, os_b, oc_w, oc_b, out);
}

// Round 13
// 485.385 us; speedup vs baseline: 1.1532x; 1.1532x over previous
//
#include <hip/hip_runtime.h>

#define DEVINL __device__ __forceinline__

// Exact (no-FMA-contraction) squared distance in the same rounding order as
// numpy/jax fp32: ((dx*dx + dy*dy) + dz*dz). Discrete decisions (FPS argmax,
// ball-query radius compare) depend on bit-exactness.
DEVINL float sq3(float ax, float ay, float az, float bx, float by, float bz) {
  float dx = __fsub_rn(ax, bx), dy = __fsub_rn(ay, by), dz = __fsub_rn(az, bz);
  return __fadd_rn(__fadd_rn(__fmul_rn(dx, dx), __fmul_rn(dy, dy)), __fmul_rn(dz, dz));
}

DEVINL float rdlane(float v, int l) {  // l compile-time const in unrolled loops
  return __int_as_float(__builtin_amdgcn_readlane(__float_as_int(v), l));
}

// DPP max-trees (VALU pipe). old=own so invalid-lane results are identity-safe
// for max. row_shr:1/2/4/8 + row_bcast:15 (+ row_bcast:31) -> 32/64-lane max;
// 64-lane result valid at lane 63 (proven rounds 4-12, absmax 0.0).
template <int CTRL>
DEVINL float dpp_maxf(float v) {
  int o = __builtin_amdgcn_update_dpp(__float_as_int(v), __float_as_int(v),
                                      CTRL, 0xf, 0xf, false);
  return fmaxf(v, __int_as_float(o));
}
DEVINL float red32_maxf(float v) {
  v = dpp_maxf<0x111>(v); v = dpp_maxf<0x112>(v); v = dpp_maxf<0x114>(v);
  v = dpp_maxf<0x118>(v); v = dpp_maxf<0x142>(v);
  return v;
}
DEVINL float red64_maxf(float v) {
  v = red32_maxf(v); v = dpp_maxf<0x143>(v);
  return v;
}
template <int CTRL>
DEVINL unsigned long long dpp_maxk(unsigned long long k) {
  const unsigned lo = (unsigned)k, hi = (unsigned)(k >> 32);
  const unsigned olo = (unsigned)__builtin_amdgcn_update_dpp(
      (int)lo, (int)lo, CTRL, 0xf, 0xf, false);
  const unsigned ohi = (unsigned)__builtin_amdgcn_update_dpp(
      (int)hi, (int)hi, CTRL, 0xf, 0xf, false);
  const unsigned long long ok = ((unsigned long long)ohi << 32) | olo;
  return (ok > k) ? ok : k;
}
DEVINL unsigned long long red64_maxk(unsigned long long k) {
  k = dpp_maxk<0x111>(k); k = dpp_maxk<0x112>(k); k = dpp_maxk<0x114>(k);
  k = dpp_maxk<0x118>(k); k = dpp_maxk<0x142>(k); k = dpp_maxk<0x143>(k);
  return k;
}

// ---------------------------------------------------------------------------
// K1: farthest point sampling — EXACT round-6 kernel (measured 243-244 us).
// CLOSED: 1-wave (378), 8-wave (265), lane-major+ballot (258), and
// register-coord-carry (295) all regressed vs this 4-wave x 8-pt structure
// with packed-u64 DPP tree + lane-63 publish + coord-carry through the
// 4-entry combine. The ~1150 cy/step is barrier/scheduling-dominated.
// ---------------------------------------------------------------------------
__global__ __launch_bounds__(256) void k_fps(const float* __restrict__ xyz,
                                             int* __restrict__ fidx) {
  const int b = blockIdx.x, t = threadIdx.x;
  __shared__ float xs[2048], ys[2048], zs[2048];
  __shared__ unsigned long long skey[2][4];
  __shared__ float4 scoord[2][4];
  const float* P = xyz + (size_t)b * 6144;
  for (int i = t; i < 2048; i += 256) {
    xs[i] = P[3 * i]; ys[i] = P[3 * i + 1]; zs[i] = P[3 * i + 2];
  }
  __syncthreads();
  float px[8], py[8], pz[8], dist[8];
#pragma unroll
  for (int j = 0; j < 8; ++j) {
    const int idx = j * 256 + t;
    px[j] = xs[idx]; py[j] = ys[idx]; pz[j] = zs[idx];
    dist[j] = 1e10f;
  }
  int far = 0;
  float cx = xs[0], cy = ys[0], cz = zs[0];
  int* out = fidx + b * 512;
  for (int it = 0; it < 512; ++it) {
    if (t == 0) out[it] = far;  // emit BEFORE update (scan emits carry's far)
    float bv = -1.0f;
    int bi = 0;
#pragma unroll
    for (int j = 0; j < 8; ++j) {
      const float d = sq3(px[j], py[j], pz[j], cx, cy, cz);
      const float nd = fminf(dist[j], d);
      dist[j] = nd;
      if (nd > bv) { bv = nd; bi = j * 256 + t; }  // strict >: smallest idx kept
    }
    unsigned long long key =
        ((unsigned long long)__float_as_uint(bv) << 32) | (unsigned)(2047 - bi);
    key = red64_maxk(key);  // wave winner at lane 63
    const int par = it & 1;
    if ((t & 63) == 63) {
      const int widx = 2047 - (int)((unsigned)key & 2047u);
      skey[par][t >> 6] = key;
      scoord[par][t >> 6] = make_float4(xs[widx], ys[widx], zs[widx], 0.0f);
    }
    __syncthreads();
    unsigned long long k0 = skey[par][0], k1 = skey[par][1];
    unsigned long long k2 = skey[par][2], k3 = skey[par][3];
    float4 c0 = scoord[par][0], c1 = scoord[par][1];
    float4 c2 = scoord[par][2], c3 = scoord[par][3];
    if (k1 > k0) { k0 = k1; c0 = c1; }
    if (k3 > k2) { k2 = k3; c2 = c3; }
    if (k2 > k0) { k0 = k2; c0 = c2; }
    far = 2047 - (int)((unsigned)k0 & 2047u);
    cx = c0.x; cy = c0.y; cz = c0.z;
  }
}

// ---------------------------------------------------------------------------
// K2: ball query. One wave per centroid. Writes the first-32 ascending
// in-radius indices to gidx[g*32 + pos] and the DISTINCT count to gn[g]
// (no padding: max over duplicates == max over distinct). Every group has
// >= 1 hit (its own centroid, d2 = 0 <= r2).
// ---------------------------------------------------------------------------
__global__ __launch_bounds__(256) void k_ballq(const float* __restrict__ xyz,
                                               const int* __restrict__ fidx,
                                               float* __restrict__ new_xyz,
                                               int* __restrict__ gidx,
                                               int* __restrict__ gn) {
  const int gw = (blockIdx.x * 256 + threadIdx.x) >> 6;  // centroid id
  const int lane = threadIdx.x & 63;
  const int b = gw >> 9;
  const float* P = xyz + (size_t)b * 6144;
  const int cidx = fidx[gw];
  const float cx = P[3 * cidx], cy = P[3 * cidx + 1], cz = P[3 * cidx + 2];
  if (lane < 3) new_xyz[(size_t)gw * 3 + lane] = P[3 * cidx + lane];
  int* g = gidx + (size_t)gw * 32;
  int base = 0;
  for (int c0 = 0; c0 < 2048; c0 += 64) {
    const int idx = c0 + lane;
    const float d = sq3(cx, cy, cz, P[3 * idx], P[3 * idx + 1], P[3 * idx + 2]);
    const bool in = !(d > 0.04f);  // matches: exclude where sqr > r*r
    const unsigned long long m = __ballot(in);
    if (in) {
      const int pos = base + (int)__popcll(m & ((1ull << lane) - 1ull));
      if (pos < 32) g[pos] = idx;
    }
    base += (int)__popcll(m);
    if (base >= 32) break;  // wave-uniform
  }
  if (lane == 0) gn[gw] = (base < 32) ? base : 32;
}

// ---------------------------------------------------------------------------
// K3: SA1, one WAVE per group, distinct items looped (E[n] ~ 2-3 of max 32).
// Register-only reduction: lane d computes h0[d]; cross-lane broadcast via
// v_readlane (compile-time lane index); lane owns sv[lane] and outputs
// {lane, lane+64}, max-accumulated in 2 VGPRs. Per-wave weight preload = 192
// VGPRs (launch_bounds(256,2) -> 256 cap). No atomics (round-10 lesson:
// device-scope atomicMax = ~30B fabric RMW each -> 113MB, 364us).
// ---------------------------------------------------------------------------
__global__ __launch_bounds__(256, 2) void k_sa1g(
    const float* __restrict__ xyz, const float* __restrict__ new_xyz,
    const int* __restrict__ gidx, const int* __restrict__ gn,
    const float* __restrict__ w0, const float* __restrict__ b0,
    const float* __restrict__ w1, const float* __restrict__ b1,
    const float* __restrict__ w2, const float* __restrict__ b2,
    float* __restrict__ l1p) {
  const int wv = threadIdx.x >> 6, lane = threadIdx.x & 63;
  const int g = blockIdx.x * 4 + wv;  // group id
  const int b = g >> 9;
  float w1r[64], w2ra[64], w2rb[64];
#pragma unroll
  for (int c = 0; c < 64; ++c) w1r[c] = w1[(lane << 6) + c];
#pragma unroll
  for (int c = 0; c < 64; ++c) w2ra[c] = w2[(lane << 6) + c];
#pragma unroll
  for (int c = 0; c < 64; ++c) w2rb[c] = w2[((lane + 64) << 6) + c];
  const float w0x = w0[3 * lane], w0y = w0[3 * lane + 1], w0z = w0[3 * lane + 2];
  const float b0l = b0[lane], b1l = b1[lane];
  const float b2a = b2[lane], b2b = b2[lane + 64];
  const float* P = xyz + (size_t)b * 6144;
  const float nx = new_xyz[(size_t)g * 3], ny = new_xyz[(size_t)g * 3 + 1],
              nz = new_xyz[(size_t)g * 3 + 2];
  const int n = gn[g];  // wave-uniform
  const int* items = gidx + (size_t)g * 32;
  float acca = 0.0f, accb = 0.0f;  // relu outputs >= 0 -> 0 is max-identity
  for (int i = 0; i < n; ++i) {
    const int src = items[i];  // wave-uniform
    const float x = P[3 * src] - nx, y = P[3 * src + 1] - ny,
                z = P[3 * src + 2] - nz;
    const float h = fmaxf(0.0f, fmaf(w0x, x, fmaf(w0y, y, fmaf(w0z, z, b0l))));
    float s0 = 0.f, s1 = 0.f, s2 = 0.f, s3 = 0.f;
#pragma unroll
    for (int c = 0; c < 64; c += 4) {
      s0 = fmaf(w1r[c], rdlane(h, c), s0);
      s1 = fmaf(w1r[c + 1], rdlane(h, c + 1), s1);
      s2 = fmaf(w1r[c + 2], rdlane(h, c + 2), s2);
      s3 = fmaf(w1r[c + 3], rdlane(h, c + 3), s3);
    }
    const float sv = fmaxf(0.0f, b1l + ((s0 + s1) + (s2 + s3)));
    float a0 = 0.f, a1 = 0.f, a2 = 0.f, a3 = 0.f;
    float u0 = 0.f, u1 = 0.f, u2 = 0.f, u3 = 0.f;
#pragma unroll
    for (int c = 0; c < 64; c += 4) {
      const float v0 = rdlane(sv, c), v1 = rdlane(sv, c + 1);
      const float v2 = rdlane(sv, c + 2), v3 = rdlane(sv, c + 3);
      a0 = fmaf(w2ra[c], v0, a0);
      a1 = fmaf(w2ra[c + 1], v1, a1);
      a2 = fmaf(w2ra[c + 2], v2, a2);
      a3 = fmaf(w2ra[c + 3], v3, a3);
      u0 = fmaf(w2rb[c], v0, u0);
      u1 = fmaf(w2rb[c + 1], v1, u1);
      u2 = fmaf(w2rb[c + 2], v2, u2);
      u3 = fmaf(w2rb[c + 3], v3, u3);
    }
    acca = fmaxf(acca, fmaxf(0.0f, b2a + ((a0 + a1) + (a2 + a3))));
    accb = fmaxf(accb, fmaxf(0.0f, b2b + ((u0 + u1) + (u2 + u3))));
  }
  float* outg = l1p + (size_t)g * 128;
  outg[lane] = acca;
  outg[lane + 64] = accb;
}

// ---------------------------------------------------------------------------
// SA2 layer kernels: lane = point (m), A row in registers (float4 packed
// [d/4][m][4] intermediates), weights via wave-uniform scalar path.
// Round 13: 8-dim chunks (2x grid vs round 6's 16-dim) -> 2x waves/CU for
// latency hiding. Extra full-input re-reads stay L2-resident (8MB tensor,
// 32MB aggregate L2).
// ---------------------------------------------------------------------------
__global__ __launch_bounds__(256, 2) void k_sa2_l0(
    const float* __restrict__ new_xyz, const float* __restrict__ l1p,
    const float* __restrict__ w0, const float* __restrict__ b0,
    float4* __restrict__ h0t4) {
  const int pb = blockIdx.x >> 4, ds = blockIdx.x & 15;  // 16 chunks x 8 dims
  const int t = threadIdx.x;
  const int d0 = ds * 8;
  const int m = pb * 256 + t;
  const float ax = new_xyz[(size_t)m * 3], ay = new_xyz[(size_t)m * 3 + 1],
              az = new_xyz[(size_t)m * 3 + 2];
  float4 av[32];
  const float4* lp = (const float4*)(l1p + (size_t)m * 128);
#pragma unroll
  for (int i = 0; i < 32; ++i) av[i] = lp[i];
  for (int dq = 0; dq < 2; ++dq) {
    float o[4];
#pragma unroll
    for (int k = 0; k < 4; ++k) {
      const int dd = 4 * dq + k;
      const float* wr = w0 + (size_t)(d0 + dd) * 131;
      float s = fmaf(wr[0], ax, fmaf(wr[1], ay, fmaf(wr[2], az, b0[d0 + dd])));
      float s0 = 0.f, s1 = 0.f, s2 = 0.f, s3 = 0.f;
#pragma unroll
      for (int i = 0; i < 32; ++i) {
        s0 = fmaf(wr[3 + 4 * i], av[i].x, s0);
        s1 = fmaf(wr[4 + 4 * i], av[i].y, s1);
        s2 = fmaf(wr[5 + 4 * i], av[i].z, s2);
        s3 = fmaf(wr[6 + 4 * i], av[i].w, s3);
      }
      o[k] = fmaxf(0.0f, s + ((s0 + s1) + (s2 + s3)));
    }
    h0t4[(size_t)(ds * 2 + dq) * 16384 + m] =
        make_float4(o[0], o[1], o[2], o[3]);
  }
}

__global__ __launch_bounds__(256, 2) void k_sa2_l1(
    const float4* __restrict__ h0t4, const float* __restrict__ w1,
    const float* __restrict__ b1, float4* __restrict__ h1t4) {
  const int pb = blockIdx.x >> 4, ds = blockIdx.x & 15;  // 16 chunks x 8 dims
  const int t = threadIdx.x;
  const int d0 = ds * 8;
  const int m = pb * 256 + t;
  float4 a4[32];
#pragma unroll
  for (int i = 0; i < 32; ++i) a4[i] = h0t4[(size_t)i * 16384 + m];
  for (int dq = 0; dq < 2; ++dq) {
    float o[4];
#pragma unroll
    for (int k = 0; k < 4; ++k) {
      const int dd = 4 * dq + k;
      const float* wr = w1 + (size_t)(d0 + dd) * 128;
      float s0 = 0.f, s1 = 0.f, s2 = 0.f, s3 = 0.f;
#pragma unroll
      for (int i = 0; i < 32; ++i) {
        s0 = fmaf(wr[4 * i], a4[i].x, s0);
        s1 = fmaf(wr[4 * i + 1], a4[i].y, s1);
        s2 = fmaf(wr[4 * i + 2], a4[i].z, s2);
        s3 = fmaf(wr[4 * i + 3], a4[i].w, s3);
      }
      o[k] = fmaxf(0.0f, b1[d0 + dd] + ((s0 + s1) + (s2 + s3)));
    }
    h1t4[(size_t)(ds * 2 + dq) * 16384 + m] =
        make_float4(o[0], o[1], o[2], o[3]);
  }
}

__global__ __launch_bounds__(256, 2) void k_sa2_l2max(
    const float4* __restrict__ h1t4, const float* __restrict__ w2,
    const float* __restrict__ b2, float* __restrict__ pmax) {
  const int pb = blockIdx.x >> 5, ds = blockIdx.x & 31;  // 32 chunks x 8 dims
  const int t = threadIdx.x;
  const int d0 = ds * 8;
  const int m = pb * 256 + t;
  const int b = m >> 9;
  const int wc = ((pb << 2) + (t >> 6)) & 7;  // wave-chunk within batch (0..7)
  float4 a4[32];
#pragma unroll
  for (int i = 0; i < 32; ++i) a4[i] = h1t4[(size_t)i * 16384 + m];
  for (int dq = 0; dq < 2; ++dq) {
#pragma unroll
    for (int k = 0; k < 4; ++k) {
      const int dd = 4 * dq + k;
      const float* wr = w2 + (size_t)(d0 + dd) * 128;
      float s0 = 0.f, s1 = 0.f, s2 = 0.f, s3 = 0.f;
#pragma unroll
      for (int i = 0; i < 32; ++i) {
        s0 = fmaf(wr[4 * i], a4[i].x, s0);
        s1 = fmaf(wr[4 * i + 1], a4[i].y, s1);
        s2 = fmaf(wr[4 * i + 2], a4[i].z, s2);
        s3 = fmaf(wr[4 * i + 3], a4[i].w, s3);
      }
      float v = fmaxf(0.0f, b2[d0 + dd] + ((s0 + s1) + (s2 + s3)));
      v = red64_maxf(v);  // wave max, valid at lane 63
      if ((t & 63) == 63) pmax[((size_t)(b << 3) + wc) * 256 + d0 + dd] = v;
    }
  }
}

// ---------------------------------------------------------------------------
// K7: head. One block (1 wave) per batch. obj = max over 8 wave-partials,
// pose MLP + fusion MLP + two scalar heads.
// ---------------------------------------------------------------------------
__global__ __launch_bounds__(64) void k_head(
    const float* __restrict__ pmax, const float* __restrict__ grasp,
    const float* __restrict__ initp, const float* __restrict__ finalp,
    const int* __restrict__ surf, const float* __restrict__ embi,
    const float* __restrict__ embf, const float* __restrict__ pw0,
    const float* __restrict__ pb0, const float* __restrict__ pw1,
    const float* __restrict__ pb1, const float* __restrict__ pw2,
    const float* __restrict__ pb2, const float* __restrict__ fw0,
    const float* __restrict__ fb0, const float* __restrict__ fw1,
    const float* __restrict__ fb1, const float* __restrict__ osw,
    const float* __restrict__ osb, const float* __restrict__ ocw,
    const float* __restrict__ ocb, float* __restrict__ out) {
  __shared__ float obj[256], xb[37], A0[64], A1[128], A2[128], F0[128], HID[64];
  const int b = blockIdx.x, l = threadIdx.x;
  const float* pm = pmax + (size_t)b * 2048;
  for (int e = l; e < 256; e += 64) {
    float v = pm[e];
#pragma unroll
    for (int w = 1; w < 8; ++w) v = fmaxf(v, pm[w * 256 + e]);
    obj[e] = v;
  }
  if (l < 7) xb[l] = grasp[b * 7 + l];
  else if (l < 14) xb[l] = initp[b * 7 + l - 7];
  else if (l < 21) xb[l] = finalp[b * 7 + l - 14];
  else if (l < 29) xb[l] = embi[surf[b * 2] * 8 + l - 21];
  else if (l < 37) xb[l] = embf[surf[b * 2 + 1] * 8 + l - 29];
  __syncthreads();
  {
    float s = pb0[l];
    const float* wr = pw0 + l * 37;
#pragma unroll
    for (int c = 0; c < 37; ++c) s = fmaf(xb[c], wr[c], s);
    A0[l] = fmaxf(0.f, s);
  }
  __syncthreads();
#pragma unroll
  for (int dd = 0; dd < 2; ++dd) {
    const int d = l + dd * 64;
    float s = pb1[d];
    const float* wr = pw1 + d * 64;
#pragma unroll
    for (int c = 0; c < 64; ++c) s = fmaf(A0[c], wr[c], s);
    A1[d] = fmaxf(0.f, s);
  }
  __syncthreads();
#pragma unroll
  for (int dd = 0; dd < 2; ++dd) {
    const int d = l + dd * 64;
    float s = pb2[d];
    const float* wr = pw2 + d * 128;
#pragma unroll 16
    for (int c = 0; c < 128; ++c) s = fmaf(A1[c], wr[c], s);
    A2[d] = fmaxf(0.f, s);
  }
  __syncthreads();
#pragma unroll
  for (int dd = 0; dd < 2; ++dd) {
    const int d = l + dd * 64;
    float s = fb0[d];
    const float* wr = fw0 + d * 384;
#pragma unroll 16
    for (int c = 0; c < 256; ++c) s = fmaf(obj[c], wr[c], s);
#pragma unroll 16
    for (int c = 0; c < 128; ++c) s = fmaf(A2[c], wr[256 + c], s);
    F0[d] = fmaxf(0.f, s);
  }
  __syncthreads();
  {
    float s = fb1[l];
    const float* wr = fw1 + l * 128;
#pragma unroll 16
    for (int c = 0; c < 128; ++c) s = fmaf(F0[c], wr[c], s);
    HID[l] = fmaxf(0.f, s);
  }
  __syncthreads();
  float v1 = HID[l] * osw[l];
  float v2 = HID[l] * ocw[l];
#pragma unroll
  for (int off = 1; off < 64; off <<= 1) {
    v1 += __shfl_xor(v1, off);
    v2 += __shfl_xor(v2, off);
  }
  if (l == 0) {
    out[b] = v1 + osb[0];
    out[32 + b] = v2 + ocb[0];
  }
}

extern "C" void kernel_launch(void* const* d_in, const int* in_sizes, int n_in,
                              void* d_out, int out_size, void* d_ws, size_t ws_size,
                              hipStream_t stream) {
  const float* points  = (const float*)d_in[0];
  const float* grasp   = (const float*)d_in[1];
  const float* initp   = (const float*)d_in[2];
  const float* finalp  = (const float*)d_in[3];
  const int*   surf    = (const int*)d_in[4];
  const float* sa1_w0  = (const float*)d_in[5];
  const float* sa1_b0  = (const float*)d_in[6];
  const float* sa1_w1  = (const float*)d_in[7];
  const float* sa1_b1  = (const float*)d_in[8];
  const float* sa1_w2  = (const float*)d_in[9];
  const float* sa1_b2  = (const float*)d_in[10];
  const float* sa2_w0  = (const float*)d_in[11];
  const float* sa2_b0  = (const float*)d_in[12];
  const float* sa2_w1  = (const float*)d_in[13];
  const float* sa2_b1  = (const float*)d_in[14];
  const float* sa2_w2  = (const float*)d_in[15];
  const float* sa2_b2  = (const float*)d_in[16];
  const float* embi    = (const float*)d_in[17];
  const float* embf    = (const float*)d_in[18];
  const float* pe_w0   = (const float*)d_in[19];
  const float* pe_b0   = (const float*)d_in[20];
  const float* pe_w1   = (const float*)d_in[21];
  const float* pe_b1   = (const float*)d_in[22];
  const float* pe_w2   = (const float*)d_in[23];
  const float* pe_b2   = (const float*)d_in[24];
  const float* fu_w0   = (const float*)d_in[25];
  const float* fu_b0   = (const float*)d_in[26];
  const float* fu_w1   = (const float*)d_in[27];
  const float* fu_b1   = (const float*)d_in[28];
  const float* os_w    = (const float*)d_in[29];
  const float* os_b    = (const float*)d_in[30];
  const float* oc_w    = (const float*)d_in[31];
  const float* oc_b    = (const float*)d_in[32];

  char* ws = (char*)d_ws;
  // layout (bytes):
  int*    fidx    = (int*)(ws + 0);               //  65536
  float*  new_xyz = (float*)(ws + 65536);         // 196608
  int*    gidx    = (int*)(ws + 262144);          // 2097152 (16384*32*4)
  float*  l1p     = (float*)(ws + 2359296);       // 8388608 (reused as h1t)
  float4* h0t4    = (float4*)(ws + 10747904);     // 8388608
  float*  pmax    = (float*)(ws + 19136512);      // 262144
  int*    gn      = (int*)(ws + 19398656);        // 65536 -> end 19464192
  float4* h1t4    = (float4*)l1p;  // l1_points dead after k_sa2_l0

  float* out = (float*)d_out;

  k_fps<<<32, 256, 0, stream>>>(points, fidx);
  k_ballq<<<4096, 256, 0, stream>>>(points, fidx, new_xyz, gidx, gn);
  k_sa1g<<<4096, 256, 0, stream>>>(points, new_xyz, gidx, gn, sa1_w0, sa1_b0,
                                   sa1_w1, sa1_b1, sa1_w2, sa1_b2, l1p);
  k_sa2_l0<<<1024, 256, 0, stream>>>(new_xyz, l1p, sa2_w0, sa2_b0, h0t4);
  k_sa2_l1<<<1024, 256, 0, stream>>>(h0t4, sa2_w1, sa2_b1, h1t4);
  k_sa2_l2max<<<2048, 256, 0, stream>>>(h1t4, sa2_w2, sa2_b2, pmax);
  k_head<<<32, 64, 0, stream>>>(pmax, grasp, initp, finalp, surf, embi, embf,
                                pe_w0, pe_b0, pe_w1, pe_b1, pe_w2, pe_b2, fu_w0,
                                fu_b0, fu_w1, fu_b1, os_w, os_b, oc_w, oc_b, out);
}

// Round 14
// 411.338 us; speedup vs baseline: 1.3608x; 1.1800x over previous
//
#include <hip/hip_runtime.h>

#define DEVINL __device__ __forceinline__

// Exact (no-FMA-contraction) squared distance in the same rounding order as
// numpy/jax fp32: ((dx*dx + dy*dy) + dz*dz). Discrete decisions (FPS argmax,
// ball-query radius compare) depend on bit-exactness.
DEVINL float sq3(float ax, float ay, float az, float bx, float by, float bz) {
  float dx = __fsub_rn(ax, bx), dy = __fsub_rn(ay, by), dz = __fsub_rn(az, bz);
  return __fadd_rn(__fadd_rn(__fmul_rn(dx, dx), __fmul_rn(dy, dy)), __fmul_rn(dz, dz));
}

DEVINL float rdlane(float v, int l) {  // l compile-time const in unrolled loops
  return __int_as_float(__builtin_amdgcn_readlane(__float_as_int(v), l));
}

// DPP max-trees (VALU pipe). old=own so invalid-lane results are identity-safe
// for max. row_shr:1/2/4/8 + row_bcast:15 (+ row_bcast:31) -> 32/64-lane max;
// 64-lane result valid at lane 63 (proven rounds 4-13, absmax 0.0).
template <int CTRL>
DEVINL float dpp_maxf(float v) {
  int o = __builtin_amdgcn_update_dpp(__float_as_int(v), __float_as_int(v),
                                      CTRL, 0xf, 0xf, false);
  return fmaxf(v, __int_as_float(o));
}
DEVINL float red32_maxf(float v) {
  v = dpp_maxf<0x111>(v); v = dpp_maxf<0x112>(v); v = dpp_maxf<0x114>(v);
  v = dpp_maxf<0x118>(v); v = dpp_maxf<0x142>(v);
  return v;
}
DEVINL float red64_maxf(float v) {
  v = red32_maxf(v); v = dpp_maxf<0x143>(v);
  return v;
}
template <int CTRL>
DEVINL unsigned long long dpp_maxk(unsigned long long k) {
  const unsigned lo = (unsigned)k, hi = (unsigned)(k >> 32);
  const unsigned olo = (unsigned)__builtin_amdgcn_update_dpp(
      (int)lo, (int)lo, CTRL, 0xf, 0xf, false);
  const unsigned ohi = (unsigned)__builtin_amdgcn_update_dpp(
      (int)hi, (int)hi, CTRL, 0xf, 0xf, false);
  const unsigned long long ok = ((unsigned long long)ohi << 32) | olo;
  return (ok > k) ? ok : k;
}
DEVINL unsigned long long red64_maxk(unsigned long long k) {
  k = dpp_maxk<0x111>(k); k = dpp_maxk<0x112>(k); k = dpp_maxk<0x114>(k);
  k = dpp_maxk<0x118>(k); k = dpp_maxk<0x142>(k); k = dpp_maxk<0x143>(k);
  return k;
}

// ---------------------------------------------------------------------------
// K0: one-time transpose of sa1 w1 [64][64] and w2 [128][64] so k_sa1g's
// per-wave weight preload is COALESCED (lane l reads wT[c*N+l], consecutive
// addresses) instead of stride-256B (64 cache lines per load instruction).
// ---------------------------------------------------------------------------
__global__ __launch_bounds__(256) void k_wt(const float* __restrict__ w1,
                                            const float* __restrict__ w2,
                                            float* __restrict__ w1T,
                                            float* __restrict__ w2T) {
  const int i = blockIdx.x * 256 + threadIdx.x;
  if (i < 4096) {
    const int d = i >> 6, c = i & 63;
    w1T[c * 64 + d] = w1[i];
  }
  if (i < 8192) {
    const int e = i >> 6, c = i & 63;
    w2T[c * 128 + e] = w2[i];
  }
}

// ---------------------------------------------------------------------------
// K1: farthest point sampling — EXACT round-6 kernel (measured 243-244 us).
// CLOSED: 1-wave (378), 8-wave (265), lane-major+ballot (258), and
// register-coord-carry (295) all regressed vs this 4-wave x 8-pt structure
// with packed-u64 DPP tree + lane-63 publish + coord-carry through the
// 4-entry combine. The ~1150 cy/step is barrier/scheduling-dominated.
// ---------------------------------------------------------------------------
__global__ __launch_bounds__(256) void k_fps(const float* __restrict__ xyz,
                                             int* __restrict__ fidx) {
  const int b = blockIdx.x, t = threadIdx.x;
  __shared__ float xs[2048], ys[2048], zs[2048];
  __shared__ unsigned long long skey[2][4];
  __shared__ float4 scoord[2][4];
  const float* P = xyz + (size_t)b * 6144;
  for (int i = t; i < 2048; i += 256) {
    xs[i] = P[3 * i]; ys[i] = P[3 * i + 1]; zs[i] = P[3 * i + 2];
  }
  __syncthreads();
  float px[8], py[8], pz[8], dist[8];
#pragma unroll
  for (int j = 0; j < 8; ++j) {
    const int idx = j * 256 + t;
    px[j] = xs[idx]; py[j] = ys[idx]; pz[j] = zs[idx];
    dist[j] = 1e10f;
  }
  int far = 0;
  float cx = xs[0], cy = ys[0], cz = zs[0];
  int* out = fidx + b * 512;
  for (int it = 0; it < 512; ++it) {
    if (t == 0) out[it] = far;  // emit BEFORE update (scan emits carry's far)
    float bv = -1.0f;
    int bi = 0;
#pragma unroll
    for (int j = 0; j < 8; ++j) {
      const float d = sq3(px[j], py[j], pz[j], cx, cy, cz);
      const float nd = fminf(dist[j], d);
      dist[j] = nd;
      if (nd > bv) { bv = nd; bi = j * 256 + t; }  // strict >: smallest idx kept
    }
    unsigned long long key =
        ((unsigned long long)__float_as_uint(bv) << 32) | (unsigned)(2047 - bi);
    key = red64_maxk(key);  // wave winner at lane 63
    const int par = it & 1;
    if ((t & 63) == 63) {
      const int widx = 2047 - (int)((unsigned)key & 2047u);
      skey[par][t >> 6] = key;
      scoord[par][t >> 6] = make_float4(xs[widx], ys[widx], zs[widx], 0.0f);
    }
    __syncthreads();
    unsigned long long k0 = skey[par][0], k1 = skey[par][1];
    unsigned long long k2 = skey[par][2], k3 = skey[par][3];
    float4 c0 = scoord[par][0], c1 = scoord[par][1];
    float4 c2 = scoord[par][2], c3 = scoord[par][3];
    if (k1 > k0) { k0 = k1; c0 = c1; }
    if (k3 > k2) { k2 = k3; c2 = c3; }
    if (k2 > k0) { k0 = k2; c0 = c2; }
    far = 2047 - (int)((unsigned)k0 & 2047u);
    cx = c0.x; cy = c0.y; cz = c0.z;
  }
}

// ---------------------------------------------------------------------------
// K2: ball query. One wave per centroid. Writes the first-32 ascending
// in-radius indices to gidx[g*32 + pos] and the DISTINCT count to gn[g]
// (no padding: max over duplicates == max over distinct). Every group has
// >= 1 hit (its own centroid, d2 = 0 <= r2).
// ---------------------------------------------------------------------------
__global__ __launch_bounds__(256) void k_ballq(const float* __restrict__ xyz,
                                               const int* __restrict__ fidx,
                                               float* __restrict__ new_xyz,
                                               int* __restrict__ gidx,
                                               int* __restrict__ gn) {
  const int gw = (blockIdx.x * 256 + threadIdx.x) >> 6;  // centroid id
  const int lane = threadIdx.x & 63;
  const int b = gw >> 9;
  const float* P = xyz + (size_t)b * 6144;
  const int cidx = fidx[gw];
  const float cx = P[3 * cidx], cy = P[3 * cidx + 1], cz = P[3 * cidx + 2];
  if (lane < 3) new_xyz[(size_t)gw * 3 + lane] = P[3 * cidx + lane];
  int* g = gidx + (size_t)gw * 32;
  int base = 0;
  for (int c0 = 0; c0 < 2048; c0 += 64) {
    const int idx = c0 + lane;
    const float d = sq3(cx, cy, cz, P[3 * idx], P[3 * idx + 1], P[3 * idx + 2]);
    const bool in = !(d > 0.04f);  // matches: exclude where sqr > r*r
    const unsigned long long m = __ballot(in);
    if (in) {
      const int pos = base + (int)__popcll(m & ((1ull << lane) - 1ull));
      if (pos < 32) g[pos] = idx;
    }
    base += (int)__popcll(m);
    if (base >= 32) break;  // wave-uniform
  }
  if (lane == 0) gn[gw] = (base < 32) ? base : 32;
}

// ---------------------------------------------------------------------------
// K3: SA1, one WAVE per G=8 groups (round 14): the r11 version's 16384 waves
// each preloaded 48KB of weights with stride-256B lane addressing (64 cache
// lines per load instr) -> ~786MB of redundant L1/L2 traffic, the suspected
// hidden hotspot. Now: coalesced preload from TRANSPOSED weights (k_wt) +
// 8 groups amortize it (2048 waves, traffic /8, exactly 2 waves/SIMD).
// Per-group math unchanged (bit-exact): lane d computes h0[d]; readlane
// broadcast; lane owns sv[lane] and outputs {lane, lane+64}; 2-VGPR max acc.
// ---------------------------------------------------------------------------
__global__ __launch_bounds__(256, 2) void k_sa1g(
    const float* __restrict__ xyz, const float* __restrict__ new_xyz,
    const int* __restrict__ gidx, const int* __restrict__ gn,
    const float* __restrict__ w0, const float* __restrict__ b0,
    const float* __restrict__ w1T, const float* __restrict__ b1,
    const float* __restrict__ w2T, const float* __restrict__ b2,
    float* __restrict__ l1p) {
  const int wv = threadIdx.x >> 6, lane = threadIdx.x & 63;
  const int g0 = (blockIdx.x * 4 + wv) * 8;  // first group of this wave
  float w1r[64], w2ra[64], w2rb[64];
#pragma unroll
  for (int c = 0; c < 64; ++c) w1r[c] = w1T[c * 64 + lane];      // coalesced
#pragma unroll
  for (int c = 0; c < 64; ++c) w2ra[c] = w2T[c * 128 + lane];    // coalesced
#pragma unroll
  for (int c = 0; c < 64; ++c) w2rb[c] = w2T[c * 128 + 64 + lane];
  const float w0x = w0[3 * lane], w0y = w0[3 * lane + 1], w0z = w0[3 * lane + 2];
  const float b0l = b0[lane], b1l = b1[lane];
  const float b2a = b2[lane], b2b = b2[lane + 64];
  for (int gi = 0; gi < 8; ++gi) {
    const int g = g0 + gi;
    const int b = g >> 9;
    const float* P = xyz + (size_t)b * 6144;
    const float nx = new_xyz[(size_t)g * 3], ny = new_xyz[(size_t)g * 3 + 1],
                nz = new_xyz[(size_t)g * 3 + 2];
    const int n = gn[g];  // wave-uniform
    const int* items = gidx + (size_t)g * 32;
    float acca = 0.0f, accb = 0.0f;  // relu outputs >= 0 -> 0 is max-identity
    for (int i = 0; i < n; ++i) {
      const int src = items[i];  // wave-uniform
      const float x = P[3 * src] - nx, y = P[3 * src + 1] - ny,
                  z = P[3 * src + 2] - nz;
      const float h = fmaxf(0.0f, fmaf(w0x, x, fmaf(w0y, y, fmaf(w0z, z, b0l))));
      float s0 = 0.f, s1 = 0.f, s2 = 0.f, s3 = 0.f;
#pragma unroll
      for (int c = 0; c < 64; c += 4) {
        s0 = fmaf(w1r[c], rdlane(h, c), s0);
        s1 = fmaf(w1r[c + 1], rdlane(h, c + 1), s1);
        s2 = fmaf(w1r[c + 2], rdlane(h, c + 2), s2);
        s3 = fmaf(w1r[c + 3], rdlane(h, c + 3), s3);
      }
      const float sv = fmaxf(0.0f, b1l + ((s0 + s1) + (s2 + s3)));
      float a0 = 0.f, a1 = 0.f, a2 = 0.f, a3 = 0.f;
      float u0 = 0.f, u1 = 0.f, u2 = 0.f, u3 = 0.f;
#pragma unroll
      for (int c = 0; c < 64; c += 4) {
        const float v0 = rdlane(sv, c), v1 = rdlane(sv, c + 1);
        const float v2 = rdlane(sv, c + 2), v3 = rdlane(sv, c + 3);
        a0 = fmaf(w2ra[c], v0, a0);
        a1 = fmaf(w2ra[c + 1], v1, a1);
        a2 = fmaf(w2ra[c + 2], v2, a2);
        a3 = fmaf(w2ra[c + 3], v3, a3);
        u0 = fmaf(w2rb[c], v0, u0);
        u1 = fmaf(w2rb[c + 1], v1, u1);
        u2 = fmaf(w2rb[c + 2], v2, u2);
        u3 = fmaf(w2rb[c + 3], v3, u3);
      }
      acca = fmaxf(acca, fmaxf(0.0f, b2a + ((a0 + a1) + (a2 + a3))));
      accb = fmaxf(accb, fmaxf(0.0f, b2b + ((u0 + u1) + (u2 + u3))));
    }
    float* outg = l1p + (size_t)g * 128;
    outg[lane] = acca;
    outg[lane + 64] = accb;
  }
}

// ---------------------------------------------------------------------------
// SA2 layer kernels: lane = point (m), A row in registers (float4 packed
// [d/4][m][4] intermediates), weights via wave-uniform scalar path.
// 8-dim chunks (round-13 win: 2x waves/CU for latency hiding; extra re-reads
// stay L2-resident).
// ---------------------------------------------------------------------------
__global__ __launch_bounds__(256, 2) void k_sa2_l0(
    const float* __restrict__ new_xyz, const float* __restrict__ l1p,
    const float* __restrict__ w0, const float* __restrict__ b0,
    float4* __restrict__ h0t4) {
  const int pb = blockIdx.x >> 4, ds = blockIdx.x & 15;  // 16 chunks x 8 dims
  const int t = threadIdx.x;
  const int d0 = ds * 8;
  const int m = pb * 256 + t;
  const float ax = new_xyz[(size_t)m * 3], ay = new_xyz[(size_t)m * 3 + 1],
              az = new_xyz[(size_t)m * 3 + 2];
  float4 av[32];
  const float4* lp = (const float4*)(l1p + (size_t)m * 128);
#pragma unroll
  for (int i = 0; i < 32; ++i) av[i] = lp[i];
  for (int dq = 0; dq < 2; ++dq) {
    float o[4];
#pragma unroll
    for (int k = 0; k < 4; ++k) {
      const int dd = 4 * dq + k;
      const float* wr = w0 + (size_t)(d0 + dd) * 131;
      float s = fmaf(wr[0], ax, fmaf(wr[1], ay, fmaf(wr[2], az, b0[d0 + dd])));
      float s0 = 0.f, s1 = 0.f, s2 = 0.f, s3 = 0.f;
#pragma unroll
      for (int i = 0; i < 32; ++i) {
        s0 = fmaf(wr[3 + 4 * i], av[i].x, s0);
        s1 = fmaf(wr[4 + 4 * i], av[i].y, s1);
        s2 = fmaf(wr[5 + 4 * i], av[i].z, s2);
        s3 = fmaf(wr[6 + 4 * i], av[i].w, s3);
      }
      o[k] = fmaxf(0.0f, s + ((s0 + s1) + (s2 + s3)));
    }
    h0t4[(size_t)(ds * 2 + dq) * 16384 + m] =
        make_float4(o[0], o[1], o[2], o[3]);
  }
}

__global__ __launch_bounds__(256, 2) void k_sa2_l1(
    const float4* __restrict__ h0t4, const float* __restrict__ w1,
    const float* __restrict__ b1, float4* __restrict__ h1t4) {
  const int pb = blockIdx.x >> 4, ds = blockIdx.x & 15;  // 16 chunks x 8 dims
  const int t = threadIdx.x;
  const int d0 = ds * 8;
  const int m = pb * 256 + t;
  float4 a4[32];
#pragma unroll
  for (int i = 0; i < 32; ++i) a4[i] = h0t4[(size_t)i * 16384 + m];
  for (int dq = 0; dq < 2; ++dq) {
    float o[4];
#pragma unroll
    for (int k = 0; k < 4; ++k) {
      const int dd = 4 * dq + k;
      const float* wr = w1 + (size_t)(d0 + dd) * 128;
      float s0 = 0.f, s1 = 0.f, s2 = 0.f, s3 = 0.f;
#pragma unroll
      for (int i = 0; i < 32; ++i) {
        s0 = fmaf(wr[4 * i], a4[i].x, s0);
        s1 = fmaf(wr[4 * i + 1], a4[i].y, s1);
        s2 = fmaf(wr[4 * i + 2], a4[i].z, s2);
        s3 = fmaf(wr[4 * i + 3], a4[i].w, s3);
      }
      o[k] = fmaxf(0.0f, b1[d0 + dd] + ((s0 + s1) + (s2 + s3)));
    }
    h1t4[(size_t)(ds * 2 + dq) * 16384 + m] =
        make_float4(o[0], o[1], o[2], o[3]);
  }
}

__global__ __launch_bounds__(256, 2) void k_sa2_l2max(
    const float4* __restrict__ h1t4, const float* __restrict__ w2,
    const float* __restrict__ b2, float* __restrict__ pmax) {
  const int pb = blockIdx.x >> 5, ds = blockIdx.x & 31;  // 32 chunks x 8 dims
  const int t = threadIdx.x;
  const int d0 = ds * 8;
  const int m = pb * 256 + t;
  const int b = m >> 9;
  const int wc = ((pb << 2) + (t >> 6)) & 7;  // wave-chunk within batch (0..7)
  float4 a4[32];
#pragma unroll
  for (int i = 0; i < 32; ++i) a4[i] = h1t4[(size_t)i * 16384 + m];
  for (int dq = 0; dq < 2; ++dq) {
#pragma unroll
    for (int k = 0; k < 4; ++k) {
      const int dd = 4 * dq + k;
      const float* wr = w2 + (size_t)(d0 + dd) * 128;
      float s0 = 0.f, s1 = 0.f, s2 = 0.f, s3 = 0.f;
#pragma unroll
      for (int i = 0; i < 32; ++i) {
        s0 = fmaf(wr[4 * i], a4[i].x, s0);
        s1 = fmaf(wr[4 * i + 1], a4[i].y, s1);
        s2 = fmaf(wr[4 * i + 2], a4[i].z, s2);
        s3 = fmaf(wr[4 * i + 3], a4[i].w, s3);
      }
      float v = fmaxf(0.0f, b2[d0 + dd] + ((s0 + s1) + (s2 + s3)));
      v = red64_maxf(v);  // wave max, valid at lane 63
      if ((t & 63) == 63) pmax[((size_t)(b << 3) + wc) * 256 + d0 + dd] = v;
    }
  }
}

// ---------------------------------------------------------------------------
// K7: head. One block (1 wave) per batch. obj = max over 8 wave-partials,
// pose MLP + fusion MLP + two scalar heads.
// ---------------------------------------------------------------------------
__global__ __launch_bounds__(64) void k_head(
    const float* __restrict__ pmax, const float* __restrict__ grasp,
    const float* __restrict__ initp, const float* __restrict__ finalp,
    const int* __restrict__ surf, const float* __restrict__ embi,
    const float* __restrict__ embf, const float* __restrict__ pw0,
    const float* __restrict__ pb0, const float* __restrict__ pw1,
    const float* __restrict__ pb1, const float* __restrict__ pw2,
    const float* __restrict__ pb2, const float* __restrict__ fw0,
    const float* __restrict__ fb0, const float* __restrict__ fw1,
    const float* __restrict__ fb1, const float* __restrict__ osw,
    const float* __restrict__ osb, const float* __restrict__ ocw,
    const float* __restrict__ ocb, float* __restrict__ out) {
  __shared__ float obj[256], xb[37], A0[64], A1[128], A2[128], F0[128], HID[64];
  const int b = blockIdx.x, l = threadIdx.x;
  const float* pm = pmax + (size_t)b * 2048;
  for (int e = l; e < 256; e += 64) {
    float v = pm[e];
#pragma unroll
    for (int w = 1; w < 8; ++w) v = fmaxf(v, pm[w * 256 + e]);
    obj[e] = v;
  }
  if (l < 7) xb[l] = grasp[b * 7 + l];
  else if (l < 14) xb[l] = initp[b * 7 + l - 7];
  else if (l < 21) xb[l] = finalp[b * 7 + l - 14];
  else if (l < 29) xb[l] = embi[surf[b * 2] * 8 + l - 21];
  else if (l < 37) xb[l] = embf[surf[b * 2 + 1] * 8 + l - 29];
  __syncthreads();
  {
    float s = pb0[l];
    const float* wr = pw0 + l * 37;
#pragma unroll
    for (int c = 0; c < 37; ++c) s = fmaf(xb[c], wr[c], s);
    A0[l] = fmaxf(0.f, s);
  }
  __syncthreads();
#pragma unroll
  for (int dd = 0; dd < 2; ++dd) {
    const int d = l + dd * 64;
    float s = pb1[d];
    const float* wr = pw1 + d * 64;
#pragma unroll
    for (int c = 0; c < 64; ++c) s = fmaf(A0[c], wr[c], s);
    A1[d] = fmaxf(0.f, s);
  }
  __syncthreads();
#pragma unroll
  for (int dd = 0; dd < 2; ++dd) {
    const int d = l + dd * 64;
    float s = pb2[d];
    const float* wr = pw2 + d * 128;
#pragma unroll 16
    for (int c = 0; c < 128; ++c) s = fmaf(A1[c], wr[c], s);
    A2[d] = fmaxf(0.f, s);
  }
  __syncthreads();
#pragma unroll
  for (int dd = 0; dd < 2; ++dd) {
    const int d = l + dd * 64;
    float s = fb0[d];
    const float* wr = fw0 + d * 384;
#pragma unroll 16
    for (int c = 0; c < 256; ++c) s = fmaf(obj[c], wr[c], s);
#pragma unroll 16
    for (int c = 0; c < 128; ++c) s = fmaf(A2[c], wr[256 + c], s);
    F0[d] = fmaxf(0.f, s);
  }
  __syncthreads();
  {
    float s = fb1[l];
    const float* wr = fw1 + l * 128;
#pragma unroll 16
    for (int c = 0; c < 128; ++c) s = fmaf(F0[c], wr[c], s);
    HID[l] = fmaxf(0.f, s);
  }
  __syncthreads();
  float v1 = HID[l] * osw[l];
  float v2 = HID[l] * ocw[l];
#pragma unroll
  for (int off = 1; off < 64; off <<= 1) {
    v1 += __shfl_xor(v1, off);
    v2 += __shfl_xor(v2, off);
  }
  if (l == 0) {
    out[b] = v1 + osb[0];
    out[32 + b] = v2 + ocb[0];
  }
}

extern "C" void kernel_launch(void* const* d_in, const int* in_sizes, int n_in,
                              void* d_out, int out_size, void* d_ws, size_t ws_size,
                              hipStream_t stream) {
  const float* points  = (const float*)d_in[0];
  const float* grasp   = (const float*)d_in[1];
  const float* initp   = (const float*)d_in[2];
  const float* finalp  = (const float*)d_in[3];
  const int*   surf    = (const int*)d_in[4];
  const float* sa1_w0  = (const float*)d_in[5];
  const float* sa1_b0  = (const float*)d_in[6];
  const float* sa1_w1  = (const float*)d_in[7];
  const float* sa1_b1  = (const float*)d_in[8];
  const float* sa1_w2  = (const float*)d_in[9];
  const float* sa1_b2  = (const float*)d_in[10];
  const float* sa2_w0  = (const float*)d_in[11];
  const float* sa2_b0  = (const float*)d_in[12];
  const float* sa2_w1  = (const float*)d_in[13];
  const float* sa2_b1  = (const float*)d_in[14];
  const float* sa2_w2  = (const float*)d_in[15];
  const float* sa2_b2  = (const float*)d_in[16];
  const float* embi    = (const float*)d_in[17];
  const float* embf    = (const float*)d_in[18];
  const float* pe_w0   = (const float*)d_in[19];
  const float* pe_b0   = (const float*)d_in[20];
  const float* pe_w1   = (const float*)d_in[21];
  const float* pe_b1   = (const float*)d_in[22];
  const float* pe_w2   = (const float*)d_in[23];
  const float* pe_b2   = (const float*)d_in[24];
  const float* fu_w0   = (const float*)d_in[25];
  const float* fu_b0   = (const float*)d_in[26];
  const float* fu_w1   = (const float*)d_in[27];
  const float* fu_b1   = (const float*)d_in[28];
  const float* os_w    = (const float*)d_in[29];
  const float* os_b    = (const float*)d_in[30];
  const float* oc_w    = (const float*)d_in[31];
  const float* oc_b    = (const float*)d_in[32];

  char* ws = (char*)d_ws;
  // layout (bytes):
  int*    fidx    = (int*)(ws + 0);               //  65536
  float*  new_xyz = (float*)(ws + 65536);         // 196608
  int*    gidx    = (int*)(ws + 262144);          // 2097152 (16384*32*4)
  float*  l1p     = (float*)(ws + 2359296);       // 8388608 (reused as h1t)
  float4* h0t4    = (float4*)(ws + 10747904);     // 8388608
  float*  pmax    = (float*)(ws + 19136512);      // 262144
  int*    gn      = (int*)(ws + 19398656);        // 65536
  float*  w1T     = (float*)(ws + 19464192);      // 16384
  float*  w2T     = (float*)(ws + 19480576);      // 32768 -> end 19513344
  float4* h1t4    = (float4*)l1p;  // l1_points dead after k_sa2_l0

  float* out = (float*)d_out;

  k_wt<<<32, 256, 0, stream>>>(sa1_w1, sa1_w2, w1T, w2T);
  k_fps<<<32, 256, 0, stream>>>(points, fidx);
  k_ballq<<<4096, 256, 0, stream>>>(points, fidx, new_xyz, gidx, gn);
  k_sa1g<<<512, 256, 0, stream>>>(points, new_xyz, gidx, gn, sa1_w0, sa1_b0,
                                  w1T, sa1_b1, w2T, sa1_b2, l1p);
  k_sa2_l0<<<1024, 256, 0, stream>>>(new_xyz, l1p, sa2_w0, sa2_b0, h0t4);
  k_sa2_l1<<<1024, 256, 0, stream>>>(h0t4, sa2_w1, sa2_b1, h1t4);
  k_sa2_l2max<<<2048, 256, 0, stream>>>(h1t4, sa2_w2, sa2_b2, pmax);
  k_head<<<32, 64, 0, stream>>>(pmax, grasp, initp, finalp, surf, embi, embf,
                                pe_w0, pe_b0, pe_w1, pe_b1, pe_w2, pe_b2, fu_w0,
                                fu_b0, fu_w1, fu_b1, os_w, os_b, oc_w, oc_b, out);
}